// Round 4
// baseline (619.355 us; speedup 1.0000x reference)
//
#include <hip/hip_runtime.h>

// ---------------------------------------------------------------------------
// DMSRStyleConv v6: style-modulated, demodulated 3x3x3 conv.
// B=8, Cin=Cout=64, 48^3 -> 46^3 VALID, fp32 in/out.
//
//   1) prep_kernel : s = style@style_w^T+style_b; d = rsqrt(sum (w*s)^2+eps);
//                    wq[b][kc][tap][frag][lane][8] = bf16(w*s*d)   (8 blk)
//   2) xT_kernel   : xT[b][z][y][x][ci] = bf16(x)                  (13824 blk)
//   3) conv        : implicit GEMM, wave = 64co x 64sp (v4 structure).
//        v6 changes (vs v4 235us / v5 248us):
//        - software-pipelined tap loop, unroll-2 with named sets:
//          B(tap+1) ds_reads issued BEFORE tap's MFMAs; A(tap+2) global
//          loads issued right after (2-tap issue-to-use covers L2 latency).
//          v4's 1-deep A prefetch left ~700cy/tap stalls (true MFMA pipe
//          occupancy only ~10%).
//        - s_setprio(1) around MFMA clusters (independent-block regime).
//        - dropped v5's T14 reg-hold (caused FETCH/WRITE regression).
// ---------------------------------------------------------------------------

typedef __bf16 bf16x8 __attribute__((ext_vector_type(8)));
typedef float  f32x4  __attribute__((ext_vector_type(4)));

static constexpr int   B_   = 8;
static constexpr int   S_   = 512;
static constexpr int   G_   = 48;
static constexpr int   O_   = 46;
static constexpr int   TAPS = 27;
static constexpr int   SPI  = G_ * G_ * G_;   // 110592
static constexpr int   SPO  = O_ * O_ * O_;   // 97336
static constexpr float EPSV = 1e-8f;

// workspace layout (bytes)
static constexpr size_t XT_OFF   = 0;
static constexpr size_t XT_BYTES = (size_t)B_ * SPI * 64 * 2;        // 113 MB
static constexpr size_t WQ_OFF   = XT_OFF + XT_BYTES;

__device__ __forceinline__ unsigned short f2bf(float f) {
    unsigned int u = __float_as_uint(f);
    u = (u + 0x7fffu + ((u >> 16) & 1u)) >> 16;
    return (unsigned short)u;
}

// ---------------------------------------------------------------------------
// 1) prep: fused s + d + wq. grid 8 (one block per batch b), block 256.
//    wq fragment order per (b,kc,tap): [frag g][lane l][8 shorts];
//    lane l of frag g: co = g*16 + (l&15), ci_local = (l>>4)*8 + j.
// ---------------------------------------------------------------------------
__global__ __launch_bounds__(256) void prep_kernel(
    const float* __restrict__ style,
    const float* __restrict__ style_w,
    const float* __restrict__ style_b,
    const float* __restrict__ weight,
    unsigned short* __restrict__ wq)
{
    __shared__ float s_sh[64];
    __shared__ float d_sh[64];
    const int b = blockIdx.x, t = threadIdx.x;

    // ---- s[g]: 4 threads per g, 128 floats each --------------------------
    {
        const int g = t >> 2, q = t & 3;
        const float4* sp = (const float4*)(style + b * S_) + q * 32;
        const float4* wp = (const float4*)(style_w + g * S_) + q * 32;
        float acc = 0.f;
#pragma unroll
        for (int i = 0; i < 32; ++i) {
            const float4 a = sp[i], w4 = wp[i];
            acc += a.x * w4.x + a.y * w4.y + a.z * w4.z + a.w * w4.w;
        }
        acc += __shfl_xor(acc, 1);
        acc += __shfl_xor(acc, 2);
        if (q == 0) s_sh[g] = acc + style_b[g];
    }
    __syncthreads();

    // ---- d[co]: 4 threads per co, 16 ci x 27 taps each -------------------
    {
        const int co = t >> 2, q = t & 3;
        float v = 0.f;
#pragma unroll 1
        for (int j = 0; j < 16; ++j) {
            const int ci = q * 16 + j;
            const float sv = s_sh[ci];
            const float* wp = weight + (co * 64 + ci) * TAPS;
#pragma unroll
            for (int i = 0; i < TAPS; ++i) { const float x = wp[i] * sv; v += x * x; }
        }
        v += __shfl_xor(v, 1);
        v += __shfl_xor(v, 2);
        if (q == 0) d_sh[co] = rsqrtf(v + EPSV);
    }
    __syncthreads();

    // ---- wq: 512 (kc,g,l) items over 256 threads, 27 taps each -----------
#pragma unroll 1
    for (int it = 0; it < 2; ++it) {
        const int item = t + it * 256;          // kc*256 + g*64 + l
        const int kc = item >> 8;
        const int g  = (item >> 6) & 3;
        const int l  = item & 63;
        const int co = g * 16 + (l & 15);
        const int ci0 = kc * 32 + ((l >> 4) * 8);
        const float dd = d_sh[co];
#pragma unroll 1
        for (int tap = 0; tap < TAPS; ++tap) {
            unsigned int u[4];
#pragma unroll
            for (int k = 0; k < 4; ++k) {
                const int ci = ci0 + 2 * k;
                const float w0 = weight[(co * 64 + ci)     * TAPS + tap] * s_sh[ci]     * dd;
                const float w1 = weight[(co * 64 + ci + 1) * TAPS + tap] * s_sh[ci + 1] * dd;
                u[k] = (unsigned)f2bf(w0) | ((unsigned)f2bf(w1) << 16);
            }
            uint4 v; v.x = u[0]; v.y = u[1]; v.z = u[2]; v.w = u[3];
            *(uint4*)(wq + ((size_t)((b * 2 + kc) * 27 + tap)) * 2048 + (g * 64 + l) * 8) = v;
        }
    }
}

// ---------------------------------------------------------------------------
// 2) x [b][ci][sp] fp32 -> xT [b][sp][ci] bf16; grid 8*1728, block 256.
// ---------------------------------------------------------------------------
__global__ void xT_kernel(const float* __restrict__ x,
                          unsigned short* __restrict__ xT)
{
    const int blk = blockIdx.x;
    const int b = blk / 1728;
    const int sp0 = (blk - b * 1728) * 64;
    const int t = threadIdx.x;
    __shared__ float tile[64][65];

    const int cr = t >> 4;                   // 0..15
    const int s4 = (t & 15) * 4;
#pragma unroll
    for (int r = 0; r < 4; ++r) {
        const int ci = r * 16 + cr;
        const float4 v = *(const float4*)(x + ((size_t)b * 64 + ci) * SPI + sp0 + s4);
        tile[ci][s4]     = v.x;
        tile[ci][s4 + 1] = v.y;
        tile[ci][s4 + 2] = v.z;
        tile[ci][s4 + 3] = v.w;
    }
    __syncthreads();

    const int ci8 = (t & 7) * 8;
    const int spq = t >> 3;                  // 0..31
#pragma unroll
    for (int p = 0; p < 2; ++p) {
        const int sp = spq + 32 * p;
        unsigned int u[4];
#pragma unroll
        for (int k = 0; k < 4; ++k) {
            const unsigned int lo = f2bf(tile[ci8 + 2 * k][sp]);
            const unsigned int hi = f2bf(tile[ci8 + 2 * k + 1][sp]);
            u[k] = lo | (hi << 16);
        }
        uint4 v; v.x = u[0]; v.y = u[1]; v.z = u[2]; v.w = u[3];
        *(uint4*)(xT + ((size_t)b * SPI + sp0 + sp) * 64 + ci8) = v;
    }
}

// ---------------------------------------------------------------------------
// 3) conv. Block = (b, 4z x 4y x 16x) outputs x 64 cout; 4 waves, wave w
//    owns z-slice z0+w (64 sp x all 64 co). x-tile 18x6x6 sp x 32ci bf16,
//    rows stride 80 B. Tap loop software-pipelined (see header).
// ---------------------------------------------------------------------------
#define XST     80
#define XTILE_B (648 * 80)     // 51840

#define MFMA16(AS, BS)                                                        \
    do {                                                                      \
        __builtin_amdgcn_s_setprio(1);                                        \
        _Pragma("unroll")                                                     \
        for (int g_ = 0; g_ < 4; ++g_) {                                      \
            _Pragma("unroll")                                                 \
            for (int n_ = 0; n_ < 4; ++n_)                                    \
                acc[g_ * 4 + n_] = __builtin_amdgcn_mfma_f32_16x16x32_bf16(   \
                    AS[g_], BS[n_], acc[g_ * 4 + n_], 0, 0, 0);               \
        }                                                                     \
        __builtin_amdgcn_s_setprio(0);                                        \
    } while (0)

__global__ __launch_bounds__(256, 3) void conv_kernel(
    const unsigned short* __restrict__ xT,   // [8][48][48][48][64] bf16 bits
    const unsigned short* __restrict__ wq,   // [8][2][27][4][64][8] bf16 bits
    const float* __restrict__ bias,          // [64]
    float* __restrict__ out)                 // [8][64][46][46][46] fp32
{
    __shared__ __align__(16) char xs[XTILE_B];

    const int t = threadIdx.x;
    // XCD-bijective swizzle: 3456 = 8 XCD x 432; each XCD owns one batch b.
    const int p  = blockIdx.x;
    const int lg = (p & 7) * 432 + (p >> 3);
    const int xt = lg % 3;                   // 0..2
    const int r0 = lg / 3;
    const int yt = r0 % 12;                  // 0..11
    const int bz = r0 / 12;                  // 0..95
    const int b  = bz / 12, zt = bz - b * 12;
    const int x0 = xt * 16;                  // {0,16,32}; ox>=46 masked
    const int y0 = (yt < 11) ? yt * 4 : 42;  // overlap tiles: dup stores identical
    const int z0 = (zt < 11) ? zt * 4 : 42;

    const unsigned short* const xb = xT + (size_t)b * (SPI * 64);
    const unsigned short* const wb = wq + (size_t)b * (2 * TAPS * 2048);

    const int w = t >> 6, l = t & 63, kg = l >> 4, l16 = l & 15;
    const unsigned short* const wa = wb + l * 8;          // + kt*2048 + g*512
    const int bbase = (w * 108 + l16) * XST + kg * 16;    // B: dz=w, dx=l16

    f32x4 acc[16];
#pragma unroll
    for (int i = 0; i < 16; ++i) acc[i] = (f32x4){0.f, 0.f, 0.f, 0.f};

    bf16x8 aA[4], aB[4], bA[4], bB[4];

    // ---- item -> global src addr for x staging ---------------------------
    auto x_src = [&](int i, int kc) -> const uint4* {
        const int sp = i >> 2, cg = i & 3;
        const int iz = sp / 108;
        const int r1 = sp - iz * 108;
        const int iy = r1 / 18;
        const int ix = r1 - iy * 18;
        int gx = x0 + ix; if (gx > 47) gx = 47;      // clamp (masked outputs)
        return (const uint4*)(xb +
            ((((z0 + iz) * 48) + (y0 + iy)) * 48 + gx) * 64 + kc * 32 + cg * 8);
    };

#pragma unroll 1
    for (int kc = 0; kc < 2; ++kc) {
        const int base = kc * TAPS;

        // prime A for taps base+0, base+1 (global; no LDS dependency)
#pragma unroll
        for (int g = 0; g < 4; ++g) {
            aA[g] = *(const bf16x8*)(wa + (size_t)(base    ) * 2048 + g * 512);
            aB[g] = *(const bf16x8*)(wa + (size_t)(base + 1) * 2048 + g * 512);
        }

        if (kc) __syncthreads();             // prev-tile readers done

        // ---- stage x chunk: 648 sp x 32 ci --------------------------------
#pragma unroll
        for (int j = 0; j < 10; ++j) {
            const int i = t + j * 256;
            const uint4 v = *x_src(i, kc);
            *(uint4*)(xs + (i >> 2) * XST + (i & 3) * 16) = v;
        }
        if (t < 32) {
            const int i = 2560 + t;
            const uint4 v = *x_src(i, kc);
            *(uint4*)(xs + (i >> 2) * XST + (i & 3) * 16) = v;
        }
        __syncthreads();                     // x-tile visible

        // prime B for tap 0 (toff(0) = 0)
#pragma unroll
        for (int nf = 0; nf < 4; ++nf)
            bA[nf] = *(const bf16x8*)(xs + bbase + nf * (18 * XST));

#pragma unroll 1
        for (int j = 0; j < 13; ++j) {
            const int t0 = 2 * j;
            // --- half 1: compute tap t0 with (aA,bA) -----------------------
            {
                const int tb = t0 + 1;                   // B prefetch tap
                const int kz = tb / 9, rr = tb - kz * 9;
                const int ky = rr / 3, kx = rr - ky * 3;
                const int toff = (kz * 108 + ky * 18 + kx) * XST;
#pragma unroll
                for (int nf = 0; nf < 4; ++nf)
                    bB[nf] = *(const bf16x8*)(xs + toff + bbase + nf * (18 * XST));
                MFMA16(aA, bA);
                const size_t ao = (size_t)(base + t0 + 2) * 2048;
#pragma unroll
                for (int g = 0; g < 4; ++g)
                    aA[g] = *(const bf16x8*)(wa + ao + g * 512);
            }
            // --- half 2: compute tap t0+1 with (aB,bB) ---------------------
            {
                const int tb = t0 + 2;                   // B prefetch tap
                const int kz = tb / 9, rr = tb - kz * 9;
                const int ky = rr / 3, kx = rr - ky * 3;
                const int toff = (kz * 108 + ky * 18 + kx) * XST;
#pragma unroll
                for (int nf = 0; nf < 4; ++nf)
                    bA[nf] = *(const bf16x8*)(xs + toff + bbase + nf * (18 * XST));
                MFMA16(aB, bB);
                int ta = base + t0 + 3; if (ta > 53) ta = 53;   // clamp (dup)
                const size_t ao = (size_t)ta * 2048;
#pragma unroll
                for (int g = 0; g < 4; ++g)
                    aB[g] = *(const bf16x8*)(wa + ao + g * 512);
            }
        }
        // --- tail: tap 26 with (aA,bA), no prefetch ------------------------
        MFMA16(aA, bA);
    }

    // ---- epilogue: C/D col = l16 = dx (n), row = kg*4+r = co%16 ----------
    const size_t ob = (size_t)b * 64 * SPO;
    const int oz = z0 + w;
    const int ox = x0 + l16;
    if (ox < O_) {
#pragma unroll
        for (int g = 0; g < 4; ++g) {
#pragma unroll
            for (int nt = 0; nt < 4; ++nt) {
                const int oy = y0 + nt;
                const f32x4 v = acc[g * 4 + nt];
                const size_t so = (size_t)oz * 2116 + oy * 46 + ox;
#pragma unroll
                for (int r = 0; r < 4; ++r) {
                    const int co = g * 16 + kg * 4 + r;
                    out[ob + (size_t)co * SPO + so] = v[r] + bias[co];
                }
            }
        }
    }
}

// ---------------------------------------------------------------------------
extern "C" void kernel_launch(void* const* d_in, const int* in_sizes, int n_in,
                              void* d_out, int out_size, void* d_ws, size_t ws_size,
                              hipStream_t stream)
{
    const float* x       = (const float*)d_in[0];
    const float* style   = (const float*)d_in[1];
    const float* weight  = (const float*)d_in[2];
    const float* bias    = (const float*)d_in[3];
    const float* style_w = (const float*)d_in[4];
    const float* style_b = (const float*)d_in[5];
    float* out = (float*)d_out;

    char* ws = (char*)d_ws;
    unsigned short* xT  = (unsigned short*)(ws + XT_OFF);
    unsigned short* wqp = (unsigned short*)(ws + WQ_OFF);

    hipLaunchKernelGGL(prep_kernel, dim3(B_), dim3(256), 0, stream,
                       style, style_w, style_b, weight, wqp);
    hipLaunchKernelGGL(xT_kernel, dim3(B_ * (SPI / 64)), dim3(256), 0, stream,
                       x, xT);
    hipLaunchKernelGGL(conv_kernel, dim3(3456), dim3(256), 0, stream,
                       xT, wqp, bias, out);
}

// Round 5
// 555.429 us; speedup vs baseline: 1.1151x; 1.1151x over previous
//
#include <hip/hip_runtime.h>

// ---------------------------------------------------------------------------
// DMSRStyleConv v7: style-modulated, demodulated 3x3x3 conv.
// B=8, Cin=Cout=64, 48^3 -> 46^3 VALID, fp32 in/out.
//
//   1) s_kernel  : s[b][ci]  = style @ style_w^T + style_b      (512 blk x 64)
//   2) d_kernel  : d[b][co]  = rsqrt(sum (w*s)^2 + eps)         (512 blk x 64)
//   3) wq_kernel : wq[b][kc][tap][frag][lane][8] = bf16(w*s*d)  (216 blk x 256)
//   4) xT_kernel : xT[b][z][y][x][ci] = bf16(x)                 (13824 blk)
//   5) conv      : implicit GEMM, wave = 64co x 64sp, pipelined tap loop.
//        v7 changes (vs v6 conv 209us, MfmaUtil 42%, conflicts 1.42e7):
//        - XST 80 -> 64: at stride 80 the B ds_read_b128 lanes map to only
//          8 bank slots (8-way conflict, 2.94x); at 64 the wave covers a
//          contiguous 1KB -> conflict-free.
//        - stage via global_load_lds width=16 (LDS dest is now lane-linear
//          item*16): no VGPR round-trip, no ds_writes. x-tile 41.5 KB.
//        - prep fusion of v6 reverted (8-blk grid was -55us): s/d/wq split.
// ---------------------------------------------------------------------------

typedef __bf16 bf16x8 __attribute__((ext_vector_type(8)));
typedef float  f32x4  __attribute__((ext_vector_type(4)));

static constexpr int   B_   = 8;
static constexpr int   S_   = 512;
static constexpr int   G_   = 48;
static constexpr int   O_   = 46;
static constexpr int   TAPS = 27;
static constexpr int   SPI  = G_ * G_ * G_;   // 110592
static constexpr int   SPO  = O_ * O_ * O_;   // 97336
static constexpr float EPSV = 1e-8f;

// workspace layout (bytes)
static constexpr size_t XT_OFF   = 0;
static constexpr size_t XT_BYTES = (size_t)B_ * SPI * 64 * 2;        // 113 MB
static constexpr size_t WQ_OFF   = XT_OFF + XT_BYTES;
static constexpr size_t WQ_BYTES = (size_t)B_ * 2 * TAPS * 64 * 32 * 2; // 1.77 MB
static constexpr size_t S_OFF    = WQ_OFF + WQ_BYTES;
static constexpr size_t D_OFF    = S_OFF + 2048;

typedef const void __attribute__((address_space(1)))* gas_cvp;
typedef void __attribute__((address_space(3)))*       las_vp;

__device__ __forceinline__ unsigned short f2bf(float f) {
    unsigned int u = __float_as_uint(f);
    u = (u + 0x7fffu + ((u >> 16) & 1u)) >> 16;
    return (unsigned short)u;
}

// ---------------------------------------------------------------------------
// 1) s[b][g] = dot(style[b,:], style_w[g,:]) + style_b[g]; grid 512, block 64
// ---------------------------------------------------------------------------
__global__ void s_kernel(const float* __restrict__ style,
                         const float* __restrict__ style_w,
                         const float* __restrict__ style_b,
                         float* __restrict__ s_out)
{
    const int bg = blockIdx.x, b = bg >> 6, g = bg & 63, l = threadIdx.x;
    const float4* sp = (const float4*)(style + b * S_);
    const float4* wp = (const float4*)(style_w + g * S_);
    const float4 a0 = sp[l * 2], a1 = sp[l * 2 + 1];
    const float4 b0 = wp[l * 2], b1 = wp[l * 2 + 1];
    float acc = a0.x * b0.x + a0.y * b0.y + a0.z * b0.z + a0.w * b0.w
              + a1.x * b1.x + a1.y * b1.y + a1.z * b1.z + a1.w * b1.w;
#pragma unroll
    for (int m = 1; m <= 32; m <<= 1) acc += __shfl_xor(acc, m);
    if (l == 0) s_out[bg] = acc + style_b[g];
}

// ---------------------------------------------------------------------------
// 2) d[b][co] = rsqrt(sum_{ci,tap}(w[co][ci][tap]*s[b][ci])^2+eps); 512 x 64
// ---------------------------------------------------------------------------
__global__ void d_kernel(const float* __restrict__ weight,
                         const float* __restrict__ s,
                         float* __restrict__ d_out)
{
    const int bc = blockIdx.x, b = bc >> 6, co = bc & 63, ci = threadIdx.x;
    const float sv = s[b * 64 + ci];
    const float* wp = weight + (co * 64 + ci) * TAPS;
    float v = 0.f;
#pragma unroll
    for (int i = 0; i < TAPS; ++i) { const float t = wp[i] * sv; v += t * t; }
#pragma unroll
    for (int m = 1; m <= 32; m <<= 1) v += __shfl_xor(v, m);
    if (ci == 0) d_out[bc] = rsqrtf(v + EPSV);
}

// ---------------------------------------------------------------------------
// 3) wq in MFMA-fragment order. Per (b,kc,tap): 2048 bf16 laid out as
//    [frag g=0..3][lane l=0..63][8 shorts]: lane l of frag g holds
//    co = g*16 + (l&15), ci_local = (l>>4)*8 + j  (j=0..7).
//    Lane-linear: conv reads A-frags straight from global, coalesced.
// ---------------------------------------------------------------------------
__global__ void wq_kernel(const float* __restrict__ weight,
                          const float* __restrict__ s,
                          const float* __restrict__ d,
                          unsigned short* __restrict__ wq)
{
    const int blk = blockIdx.x;
    const int b = blk / 27, tap = blk - b * 27;
    const int t = threadIdx.x;
#pragma unroll
    for (int it = 0; it < 2; ++it) {
        const int item = t + it * 256;          // 0..511 = kc*256 + g*64 + l
        const int kc = item >> 8;
        const int g  = (item >> 6) & 3;
        const int l  = item & 63;
        const int co = g * 16 + (l & 15);
        const int ci0 = kc * 32 + ((l >> 4) * 8);
        const float dd = d[b * 64 + co];
        unsigned int u[4];
#pragma unroll
        for (int k = 0; k < 4; ++k) {
            const int ci = ci0 + 2 * k;
            const float w0 = weight[(co * 64 + ci)     * TAPS + tap] * s[b * 64 + ci]     * dd;
            const float w1 = weight[(co * 64 + ci + 1) * TAPS + tap] * s[b * 64 + ci + 1] * dd;
            u[k] = (unsigned)f2bf(w0) | ((unsigned)f2bf(w1) << 16);
        }
        uint4 v; v.x = u[0]; v.y = u[1]; v.z = u[2]; v.w = u[3];
        *(uint4*)(wq + ((size_t)((b * 2 + kc) * 27 + tap)) * 2048 + (g * 64 + l) * 8) = v;
    }
}

// ---------------------------------------------------------------------------
// 4) x [b][ci][sp] fp32 -> xT [b][sp][ci] bf16; grid 8*1728, block 256.
// ---------------------------------------------------------------------------
__global__ void xT_kernel(const float* __restrict__ x,
                          unsigned short* __restrict__ xT)
{
    const int blk = blockIdx.x;
    const int b = blk / 1728;
    const int sp0 = (blk - b * 1728) * 64;
    const int t = threadIdx.x;
    __shared__ float tile[64][65];

    const int cr = t >> 4;                   // 0..15
    const int s4 = (t & 15) * 4;
#pragma unroll
    for (int r = 0; r < 4; ++r) {
        const int ci = r * 16 + cr;
        const float4 v = *(const float4*)(x + ((size_t)b * 64 + ci) * SPI + sp0 + s4);
        tile[ci][s4]     = v.x;
        tile[ci][s4 + 1] = v.y;
        tile[ci][s4 + 2] = v.z;
        tile[ci][s4 + 3] = v.w;
    }
    __syncthreads();

    const int ci8 = (t & 7) * 8;
    const int spq = t >> 3;                  // 0..31
#pragma unroll
    for (int p = 0; p < 2; ++p) {
        const int sp = spq + 32 * p;
        unsigned int u[4];
#pragma unroll
        for (int k = 0; k < 4; ++k) {
            const unsigned int lo = f2bf(tile[ci8 + 2 * k][sp]);
            const unsigned int hi = f2bf(tile[ci8 + 2 * k + 1][sp]);
            u[k] = lo | (hi << 16);
        }
        uint4 v; v.x = u[0]; v.y = u[1]; v.z = u[2]; v.w = u[3];
        *(uint4*)(xT + ((size_t)b * SPI + sp0 + sp) * 64 + ci8) = v;
    }
}

// ---------------------------------------------------------------------------
// 5) conv. Block = (b, 4z x 4y x 16x) outputs x 64 cout; 4 waves, wave w
//    owns z-slice z0+w (64 sp x all 64 co). x-tile 18x6x6 sp x 32ci bf16,
//    row stride 64 B (lane-linear: item*16). Pipeline: B(tap+1) ds_reads
//    before tap's MFMAs; A(tap+2) global loads after.
// ---------------------------------------------------------------------------
#define XST     64
#define XTILE_B (648 * 64)     // 41472

#define MFMA16(AS, BS)                                                        \
    do {                                                                      \
        __builtin_amdgcn_s_setprio(1);                                        \
        _Pragma("unroll")                                                     \
        for (int g_ = 0; g_ < 4; ++g_) {                                      \
            _Pragma("unroll")                                                 \
            for (int n_ = 0; n_ < 4; ++n_)                                    \
                acc[g_ * 4 + n_] = __builtin_amdgcn_mfma_f32_16x16x32_bf16(   \
                    AS[g_], BS[n_], acc[g_ * 4 + n_], 0, 0, 0);               \
        }                                                                     \
        __builtin_amdgcn_s_setprio(0);                                        \
    } while (0)

__global__ __launch_bounds__(256, 3) void conv_kernel(
    const unsigned short* __restrict__ xT,   // [8][48][48][48][64] bf16 bits
    const unsigned short* __restrict__ wq,   // [8][2][27][4][64][8] bf16 bits
    const float* __restrict__ bias,          // [64]
    float* __restrict__ out)                 // [8][64][46][46][46] fp32
{
    __shared__ __align__(16) char xs[XTILE_B];

    const int t = threadIdx.x;
    // XCD-bijective swizzle: 3456 = 8 XCD x 432; each XCD owns one batch b.
    const int p  = blockIdx.x;
    const int lg = (p & 7) * 432 + (p >> 3);
    const int xt = lg % 3;                   // 0..2
    const int r0 = lg / 3;
    const int yt = r0 % 12;                  // 0..11
    const int bz = r0 / 12;                  // 0..95
    const int b  = bz / 12, zt = bz - b * 12;
    const int x0 = xt * 16;                  // {0,16,32}; ox>=46 masked
    const int y0 = (yt < 11) ? yt * 4 : 42;  // overlap tiles: dup stores identical
    const int z0 = (zt < 11) ? zt * 4 : 42;

    const unsigned short* const xb = xT + (size_t)b * (SPI * 64);
    const unsigned short* const wb = wq + (size_t)b * (2 * TAPS * 2048);

    const int w = t >> 6, l = t & 63, kg = l >> 4, l16 = l & 15;
    const unsigned short* const wa = wb + l * 8;          // + kt*2048 + g*512
    const int bbase = (w * 108 + l16) * XST + kg * 16;    // B: dz=w, dx=l16

    f32x4 acc[16];
#pragma unroll
    for (int i = 0; i < 16; ++i) acc[i] = (f32x4){0.f, 0.f, 0.f, 0.f};

    bf16x8 aA[4], aB[4], bA[4], bB[4];

    // ---- item -> global src addr for x staging ---------------------------
    auto x_src = [&](int i, int kc) -> const uint4* {
        const int sp = i >> 2, cg = i & 3;
        const int iz = sp / 108;
        const int r1 = sp - iz * 108;
        const int iy = r1 / 18;
        const int ix = r1 - iy * 18;
        int gx = x0 + ix; if (gx > 47) gx = 47;      // clamp (masked outputs)
        return (const uint4*)(xb +
            ((((z0 + iz) * 48) + (y0 + iy)) * 48 + gx) * 64 + kc * 32 + cg * 8);
    };

#pragma unroll 1
    for (int kc = 0; kc < 2; ++kc) {
        const int base = kc * TAPS;

        // prime A for taps base+0, base+1 (global; no LDS dependency)
#pragma unroll
        for (int g = 0; g < 4; ++g) {
            aA[g] = *(const bf16x8*)(wa + (size_t)(base    ) * 2048 + g * 512);
            aB[g] = *(const bf16x8*)(wa + (size_t)(base + 1) * 2048 + g * 512);
        }

        if (kc) __syncthreads();             // prev-tile readers done

        // ---- stage x chunk: 648 sp x 32 ci, direct global->LDS ------------
        // item i lands at LDS byte i*16: wave-uniform base + lane*16.
#pragma unroll
        for (int j = 0; j < 10; ++j) {
            const int i = t + j * 256;
            __builtin_amdgcn_global_load_lds((gas_cvp)x_src(i, kc),
                                             (las_vp)(xs + i * 16), 16, 0, 0);
        }
        if (t < 32) {                        // 32-item tail (plain path)
            const int i = 2560 + t;
            const uint4 v = *x_src(i, kc);
            *(uint4*)(xs + i * 16) = v;
        }
        __syncthreads();                     // x-tile visible

        // prime B for tap 0 (toff(0) = 0)
#pragma unroll
        for (int nf = 0; nf < 4; ++nf)
            bA[nf] = *(const bf16x8*)(xs + bbase + nf * (18 * XST));

#pragma unroll 1
        for (int j = 0; j < 13; ++j) {
            const int t0 = 2 * j;
            // --- half 1: compute tap t0 with (aA,bA) -----------------------
            {
                const int tb = t0 + 1;                   // B prefetch tap
                const int kz = tb / 9, rr = tb - kz * 9;
                const int ky = rr / 3, kx = rr - ky * 3;
                const int toff = (kz * 108 + ky * 18 + kx) * XST;
#pragma unroll
                for (int nf = 0; nf < 4; ++nf)
                    bB[nf] = *(const bf16x8*)(xs + toff + bbase + nf * (18 * XST));
                MFMA16(aA, bA);
                const size_t ao = (size_t)(base + t0 + 2) * 2048;
#pragma unroll
                for (int g = 0; g < 4; ++g)
                    aA[g] = *(const bf16x8*)(wa + ao + g * 512);
            }
            // --- half 2: compute tap t0+1 with (aB,bB) ---------------------
            {
                const int tb = t0 + 2;                   // B prefetch tap
                const int kz = tb / 9, rr = tb - kz * 9;
                const int ky = rr / 3, kx = rr - ky * 3;
                const int toff = (kz * 108 + ky * 18 + kx) * XST;
#pragma unroll
                for (int nf = 0; nf < 4; ++nf)
                    bA[nf] = *(const bf16x8*)(xs + toff + bbase + nf * (18 * XST));
                MFMA16(aB, bB);
                int ta = base + t0 + 3; if (ta > 53) ta = 53;   // clamp (dup)
                const size_t ao = (size_t)ta * 2048;
#pragma unroll
                for (int g = 0; g < 4; ++g)
                    aB[g] = *(const bf16x8*)(wa + ao + g * 512);
            }
        }
        // --- tail: tap 26 with (aA,bA), no prefetch ------------------------
        MFMA16(aA, bA);
    }

    // ---- epilogue: C/D col = l16 = dx (n), row = kg*4+r = co%16 ----------
    const size_t ob = (size_t)b * 64 * SPO;
    const int oz = z0 + w;
    const int ox = x0 + l16;
    if (ox < O_) {
#pragma unroll
        for (int g = 0; g < 4; ++g) {
#pragma unroll
            for (int nt = 0; nt < 4; ++nt) {
                const int oy = y0 + nt;
                const f32x4 v = acc[g * 4 + nt];
                const size_t so = (size_t)oz * 2116 + oy * 46 + ox;
#pragma unroll
                for (int r = 0; r < 4; ++r) {
                    const int co = g * 16 + kg * 4 + r;
                    out[ob + (size_t)co * SPO + so] = v[r] + bias[co];
                }
            }
        }
    }
}

// ---------------------------------------------------------------------------
extern "C" void kernel_launch(void* const* d_in, const int* in_sizes, int n_in,
                              void* d_out, int out_size, void* d_ws, size_t ws_size,
                              hipStream_t stream)
{
    const float* x       = (const float*)d_in[0];
    const float* style   = (const float*)d_in[1];
    const float* weight  = (const float*)d_in[2];
    const float* bias    = (const float*)d_in[3];
    const float* style_w = (const float*)d_in[4];
    const float* style_b = (const float*)d_in[5];
    float* out = (float*)d_out;

    char* ws = (char*)d_ws;
    unsigned short* xT  = (unsigned short*)(ws + XT_OFF);
    unsigned short* wqp = (unsigned short*)(ws + WQ_OFF);
    float* sbuf = (float*)(ws + S_OFF);
    float* dbuf = (float*)(ws + D_OFF);

    hipLaunchKernelGGL(s_kernel, dim3(512), dim3(64), 0, stream,
                       style, style_w, style_b, sbuf);
    hipLaunchKernelGGL(d_kernel, dim3(512), dim3(64), 0, stream,
                       weight, sbuf, dbuf);
    hipLaunchKernelGGL(wq_kernel, dim3(216), dim3(256), 0, stream,
                       weight, sbuf, dbuf, wqp);
    hipLaunchKernelGGL(xT_kernel, dim3(B_ * (SPI / 64)), dim3(256), 0, stream,
                       x, xT);
    hipLaunchKernelGGL(conv_kernel, dim3(3456), dim3(256), 0, stream,
                       xT, wqp, bias, out);
}